// Round 27
// baseline (98.209 us; speedup 1.0000x reference)
//
#include <hip/hip_runtime.h>
#include <hip/hip_bf16.h>
#include <stdint.h>
#include <math.h>

#define B_ 2
#define T_ 2048
#define C_ 1024
#define H_ 16
#define HD_ 64
#define BT_ (B_*T_)      // 4096 rows
#define N1_ (3*C_)       // 3072

typedef unsigned short u16;
typedef uint32_t u32;
typedef __attribute__((ext_vector_type(8))) short bf16x8;
typedef __attribute__((ext_vector_type(4))) float f32x4;
typedef __attribute__((ext_vector_type(16))) float f32x16;
typedef __attribute__((ext_vector_type(4))) unsigned int u32x4;

__device__ __forceinline__ u16 f2bf(float f) {
  __hip_bfloat16 h = __float2bfloat16(f);
  return *reinterpret_cast<u16*>(&h);
}
__device__ __forceinline__ float bf2f(u16 u) {
  u32 w = ((u32)u) << 16;
  return *reinterpret_cast<float*>(&w);
}
__device__ __forceinline__ u32 cvtpk(float lo, float hi) {
  u32 r;
  asm("v_cvt_pk_bf16_f32 %0, %1, %2" : "=v"(r) : "v"(lo), "v"(hi));
  return r;
}
__device__ __forceinline__ float exp2v(float x) {   // exact v_exp_f32 (2^x); -inf -> 0
  float r;
  asm("v_exp_f32 %0, %1" : "=v"(r) : "v"(x));
  return r;
}

__device__ __forceinline__ void gload_lds16(const void* g, void* l) {
  __builtin_amdgcn_global_load_lds(
      (const __attribute__((address_space(1))) uint32_t*)g,
      (__attribute__((address_space(3))) uint32_t*)l, 16, 0, 0);
}

// raw workgroup barrier WITHOUT __syncthreads' vmcnt(0) drain
#define BARX() do { asm volatile("" ::: "memory"); __builtin_amdgcn_s_barrier(); \
                    asm volatile("" ::: "memory"); } while (0)
// lgkm drain + scheduler fence (rule #18)
#define LGKM0() do { asm volatile("s_waitcnt lgkmcnt(0)" ::: "memory"); \
                     __builtin_amdgcn_sched_barrier(0); } while (0)

// ---------------- fused prep: cast x + transpose-cast both weights ----------------
__global__ __launch_bounds__(256) void prep_k(const float* __restrict__ x,
                                              const float* __restrict__ w_qkv,
                                              const float* __restrict__ w_out,
                                              u16* __restrict__ xb,
                                              u16* __restrict__ wqkvT,
                                              u16* __restrict__ woutT) {
  __shared__ float tile[32][33];
  int bid = blockIdx.x;
  if (bid < 4096) {
    int idx = bid * 1024 + threadIdx.x * 4;
    float4 v = *reinterpret_cast<const float4*>(x + idx);
    u16 tmp[4] = {f2bf(v.x), f2bf(v.y), f2bf(v.z), f2bf(v.w)};
    *reinterpret_cast<uint2*>(xb + idx) = *reinterpret_cast<const uint2*>(tmp);
    return;
  }
  const float* w;
  u16* wt;
  int N, tb;
  if (bid < 7168) { tb = bid - 4096; w = w_qkv; wt = wqkvT; N = N1_; }
  else            { tb = bid - 7168; w = w_out; wt = woutT; N = C_;  }
  int nx = N >> 5;
  int n0 = (tb % nx) * 32, k0 = (tb / nx) * 32;
  int tx = threadIdx.x & 31, ty = threadIdx.x >> 5;
#pragma unroll
  for (int i = 0; i < 4; i++)
    tile[ty + i*8][tx] = w[(size_t)(k0 + ty + i*8) * N + n0 + tx];
  __syncthreads();
#pragma unroll
  for (int i = 0; i < 4; i++)
    wt[(size_t)(n0 + ty + i*8) * 1024 + k0 + tx] = f2bf(tile[tx][ty + i*8]);
}

// ---------------- QKV GEMM: 256x192, BK=64, 2-phase choreography (R19-proven) ----------------
__global__ __launch_bounds__(512, 2) void gemm256(const u16* __restrict__ A, const u16* __restrict__ Bt,
                                                  u16* __restrict__ Cc) {
  __shared__ u16 As[2][256*64];
  __shared__ u16 Bs[2][192*64];
  int tid = threadIdx.x, w = tid >> 6, lane = tid & 63;
  int m0 = blockIdx.y * 256, n0 = blockIdx.x * 192;
  int wm = (w >> 2) * 128, wn = (w & 3) * 48;
  f32x4 acc[8][3] = {};

  size_t aoff[4];
  size_t boff[3];
#pragma unroll
  for (int i = 0; i < 4; i++) {
    int c = i*512 + tid, row = c >> 3;
    aoff[i] = (size_t)(m0 + row) * 1024 + (size_t)((((c & 7) ^ (row & 7))) * 8);
  }
#pragma unroll
  for (int i = 0; i < 3; i++) {
    int c = i*512 + tid, row = c >> 3;
    boff[i] = (size_t)(n0 + row) * 1024 + (size_t)((((c & 7) ^ (row & 7))) * 8);
  }
  int dstc = w * 1024;

  int r15 = lane & 15, kq = lane >> 4;
  int slot0 = (kq ^ (r15 & 7)) * 8;
  int abase = (wm + r15) * 64;
  int bbase = (wn + r15) * 64;

#pragma unroll
  for (int i = 0; i < 4; i++)
    gload_lds16(A + aoff[i], (char*)&As[0][0] + i*8192 + dstc);
#pragma unroll
  for (int i = 0; i < 3; i++)
    gload_lds16(Bt + boff[i], (char*)&Bs[0][0] + i*8192 + dstc);

  for (int t = 0; t < 16; ++t) {
    int buf = t & 1;
    const u16* Ab = &As[buf][0];
    const u16* Bb = &Bs[buf][0];
    int slot1 = slot0 ^ 32;
    bf16x8 af[8], bfv[3];

    asm volatile("s_waitcnt vmcnt(0)" ::: "memory");
    BARX();

#pragma unroll
    for (int nf = 0; nf < 3; nf++) bfv[nf] = *reinterpret_cast<const bf16x8*>(&Bb[bbase + nf*1024 + slot0]);
#pragma unroll
    for (int mf = 0; mf < 8; mf++) af[mf] = *reinterpret_cast<const bf16x8*>(&Ab[abase + mf*1024 + slot0]);
    if (t < 15) {
      int ko = (t + 1) * 64;
#pragma unroll
      for (int i = 0; i < 4; i++)
        gload_lds16(A + aoff[i] + ko, (char*)&As[buf ^ 1][0] + i*8192 + dstc);
#pragma unroll
      for (int i = 0; i < 3; i++)
        gload_lds16(Bt + boff[i] + ko, (char*)&Bs[buf ^ 1][0] + i*8192 + dstc);
    }
    BARX();
    LGKM0();
    __builtin_amdgcn_s_setprio(1);
#pragma unroll
    for (int mf = 0; mf < 8; mf++)
#pragma unroll
      for (int nf = 0; nf < 3; nf++)
        acc[mf][nf] = __builtin_amdgcn_mfma_f32_16x16x32_bf16(af[mf], bfv[nf], acc[mf][nf], 0, 0, 0);
    __builtin_amdgcn_s_setprio(0);

#pragma unroll
    for (int nf = 0; nf < 3; nf++) bfv[nf] = *reinterpret_cast<const bf16x8*>(&Bb[bbase + nf*1024 + slot1]);
#pragma unroll
    for (int mf = 0; mf < 8; mf++) af[mf] = *reinterpret_cast<const bf16x8*>(&Ab[abase + mf*1024 + slot1]);
    BARX();
    LGKM0();
    __builtin_amdgcn_s_setprio(1);
#pragma unroll
    for (int mf = 0; mf < 8; mf++)
#pragma unroll
      for (int nf = 0; nf < 3; nf++)
        acc[mf][nf] = __builtin_amdgcn_mfma_f32_16x16x32_bf16(af[mf], bfv[nf], acc[mf][nf], 0, 0, 0);
    __builtin_amdgcn_s_setprio(0);
  }

  int rg = kq * 4;
#pragma unroll
  for (int mf = 0; mf < 8; mf++)
#pragma unroll
    for (int nf = 0; nf < 3; nf++) {
      size_t basei = (size_t)(m0 + wm + mf*16 + rg) * N1_ + (size_t)(n0 + wn + nf*16 + r15);
#pragma unroll
      for (int r = 0; r < 4; r++)
        Cc[basei + (size_t)r * N1_] = f2bf(acc[mf][nf][r]);
    }
}

// ---------------- out-proj GEMM: 128x128, BK=64, 8 waves (R22-proven) ----------------
__global__ __launch_bounds__(512, 1) void gemm128(const u16* __restrict__ A, const u16* __restrict__ Bt,
                                                  float* __restrict__ Co) {
  __shared__ u16 As[2][128*64];
  __shared__ u16 Bs[2][128*64];
  int tid = threadIdx.x, w = tid >> 6, lane = tid & 63;
  int m0 = blockIdx.y * 128, n0 = blockIdx.x * 128;
  int wm = (w >> 2) * 64, wn = (w & 3) * 32;
  f32x4 acc[4][2] = {};

  size_t aoff[2], boff[2];
#pragma unroll
  for (int i = 0; i < 2; i++) {
    int c = i*512 + tid, row = c >> 3;
    aoff[i] = (size_t)(m0 + row) * 1024 + (size_t)((((c & 7) ^ (row & 7))) * 8);
    boff[i] = (size_t)(n0 + row) * 1024 + (size_t)((((c & 7) ^ (row & 7))) * 8);
  }
  int dstc = w * 1024;

  int r15 = lane & 15, kq = lane >> 4;
  int slot0 = (kq ^ (r15 & 7)) * 8;
  int abase = (wm + r15) * 64;
  int bbase = (wn + r15) * 64;

#pragma unroll
  for (int i = 0; i < 2; i++) {
    gload_lds16(A  + aoff[i], (char*)&As[0][0] + i*8192 + dstc);
    gload_lds16(Bt + boff[i], (char*)&Bs[0][0] + i*8192 + dstc);
  }

  for (int t = 0; t < 16; ++t) {
    int buf = t & 1;
    const u16* Ab = &As[buf][0];
    const u16* Bb = &Bs[buf][0];
    int slot1 = slot0 ^ 32;
    bf16x8 af[4], bfv[2];

    asm volatile("s_waitcnt vmcnt(0)" ::: "memory");
    BARX();

#pragma unroll
    for (int nf = 0; nf < 2; nf++) bfv[nf] = *reinterpret_cast<const bf16x8*>(&Bb[bbase + nf*1024 + slot0]);
#pragma unroll
    for (int mf = 0; mf < 4; mf++) af[mf] = *reinterpret_cast<const bf16x8*>(&Ab[abase + mf*1024 + slot0]);
    if (t < 15) {
      int ko = (t + 1) * 64;
#pragma unroll
      for (int i = 0; i < 2; i++) {
        gload_lds16(A  + aoff[i] + ko, (char*)&As[buf ^ 1][0] + i*8192 + dstc);
        gload_lds16(Bt + boff[i] + ko, (char*)&Bs[buf ^ 1][0] + i*8192 + dstc);
      }
    }
    BARX();
    LGKM0();
    __builtin_amdgcn_s_setprio(1);
#pragma unroll
    for (int mf = 0; mf < 4; mf++)
#pragma unroll
      for (int nf = 0; nf < 2; nf++)
        acc[mf][nf] = __builtin_amdgcn_mfma_f32_16x16x32_bf16(af[mf], bfv[nf], acc[mf][nf], 0, 0, 0);
    __builtin_amdgcn_s_setprio(0);

#pragma unroll
    for (int nf = 0; nf < 2; nf++) bfv[nf] = *reinterpret_cast<const bf16x8*>(&Bb[bbase + nf*1024 + slot1]);
#pragma unroll
    for (int mf = 0; mf < 4; mf++) af[mf] = *reinterpret_cast<const bf16x8*>(&Ab[abase + mf*1024 + slot1]);
    BARX();
    LGKM0();
    __builtin_amdgcn_s_setprio(1);
#pragma unroll
    for (int mf = 0; mf < 4; mf++)
#pragma unroll
      for (int nf = 0; nf < 2; nf++)
        acc[mf][nf] = __builtin_amdgcn_mfma_f32_16x16x32_bf16(af[mf], bfv[nf], acc[mf][nf], 0, 0, 0);
    __builtin_amdgcn_s_setprio(0);
  }

  int rg = kq * 4;
#pragma unroll
  for (int mf = 0; mf < 4; mf++)
#pragma unroll
    for (int nf = 0; nf < 2; nf++) {
      size_t basei = (size_t)(m0 + wm + mf*16 + rg) * C_ + (size_t)(n0 + wn + nf*16 + r15);
#pragma unroll
      for (int r = 0; r < 4; r++)
        Co[basei + (size_t)r * C_] = acc[mf][nf][r];
    }
}

// ---------------- causal flash attention: R26 structure + setprio (T5) ----------------
// 1024 x 256thr, 4-way key split, dual-strip shared-K/V, linear-V via gload_lds,
// scalar-u16 PV reads (2-way bank = free). NEW: s_setprio(1) around QK and PV
// MFMA clusters -- attn blocks run independent phases, the m191-measured regime
// where setprio arbitration pays (+4-7%).
__global__ __launch_bounds__(256, 2) void attn_kernel(const u16* __restrict__ qkv, u16* __restrict__ attnout) {
  __shared__ u16 Sm[4][4096];    // per wave: K tile [0..2047], V tile linear [2048..4095]
  int tid = threadIdx.x;
  int w = tid >> 6, lane = tid & 63;
  int q31 = lane & 31, hi = lane >> 5;
  int lid = blockIdx.x;
  int xcd = lid & 7, j = lid >> 3;
  int bh = xcd * 4 + (j & 3);
  int p = j >> 2;                // 0..31
  int b = bh >> 4, h = bh & 15;
  const u16* base = qkv + (size_t)b * T_ * N1_;

  u16* Ks = Sm[w];
  u16* Vl = Sm[w] + 2048;

  const u16* ksrc = base + C_ + h*HD_ + (size_t)(lane >> 3) * N1_
                    + (size_t)(((lane & 7) ^ ((lane >> 3) & 7)) * 8);
  const u16* vsrc = base + 2*C_ + h*HD_ + (size_t)(lane >> 3) * N1_
                    + (size_t)((lane & 7) * 8);
  const float QSC = 0.125f * 1.44269504088896f;

  int sA = 63 - p, sB = p;
  int qgA = sA * 32 + q31, qgB = sB * 32 + q31;
  int nktU = sA + 1;             // >= 33, all 4 waves active

  bf16x8 qfA[4], qfB[4];
  {
    const u16* qrowA = base + (size_t)qgA * N1_ + h * HD_;
    const u16* qrowB = base + (size_t)qgB * N1_ + h * HD_;
#pragma unroll
    for (int kk = 0; kk < 4; kk++) {
      bf16x8 ra = *reinterpret_cast<const bf16x8*>(qrowA + kk*16 + hi*8);
      bf16x8 rb = *reinterpret_cast<const bf16x8*>(qrowB + kk*16 + hi*8);
      const u16* pa = (const u16*)&ra;
      const u16* pb = (const u16*)&rb;
      u32x4 qa, qb;
#pragma unroll
      for (int jj = 0; jj < 4; jj++) {
        qa[jj] = cvtpk(bf2f(pa[2*jj]) * QSC, bf2f(pa[2*jj+1]) * QSC);
        qb[jj] = cvtpk(bf2f(pb[2*jj]) * QSC, bf2f(pb[2*jj+1]) * QSC);
      }
      qfA[kk] = __builtin_bit_cast(bf16x8, qa);
      qfB[kk] = __builtin_bit_cast(bf16x8, qb);
    }
  }

  f32x16 oaccA[2] = {}, oaccB[2] = {};
  float lA = 0.f, lB = 0.f;

  // ---- prologue: stage K(w) then V(w) via gload_lds (8 outstanding) ----
  {
    size_t off0 = (size_t)(w * 32) * N1_;
#pragma unroll
    for (int r = 0; r < 4; r++)
      gload_lds16(ksrc + off0 + (size_t)(8*r) * N1_, (char*)Ks + r*1024);
#pragma unroll
    for (int r = 0; r < 4; r++)
      gload_lds16(vsrc + off0 + (size_t)(8*r) * N1_, (char*)Vl + r*1024);
  }

  for (int kt = w; kt < nktU; kt += 4) {
    int kb = kt * 32;
    bool lastown = (kt + 4 >= nktU);
    bool actB = (kt <= sB);

    // ---- K(t) landed (V(t) + any K(t+4) remain countable) ----
    asm volatile("s_waitcnt vmcnt(4)" ::: "memory");

    // ---- QK^T (kf read once, both strips) ----
    f32x16 stA = {}, stB = {};
    __builtin_amdgcn_s_setprio(1);
    if (actB) {
#pragma unroll
      for (int kk = 0; kk < 4; kk++) {
        bf16x8 kf = *reinterpret_cast<const bf16x8*>(
            &Ks[q31*64 + ((((kk<<1) | hi) ^ (q31 & 7)) << 3)]);
        stA = __builtin_amdgcn_mfma_f32_32x32x16_bf16(kf, qfA[kk], stA, 0, 0, 0);
        stB = __builtin_amdgcn_mfma_f32_32x32x16_bf16(kf, qfB[kk], stB, 0, 0, 0);
      }
    } else {
#pragma unroll
      for (int kk = 0; kk < 4; kk++) {
        bf16x8 kf = *reinterpret_cast<const bf16x8*>(
            &Ks[q31*64 + ((((kk<<1) | hi) ^ (q31 & 7)) << 3)]);
        stA = __builtin_amdgcn_mfma_f32_32x32x16_bf16(kf, qfA[kk], stA, 0, 0, 0);
      }
    }
    __builtin_amdgcn_s_setprio(0);
    asm volatile("s_waitcnt lgkmcnt(0)" ::: "memory");   // Ks reads retired
    __builtin_amdgcn_sched_barrier(0);

    // ---- prefetch K(t+4) into Ks (safe: QK reads drained) ----
    if (!lastown) {
      size_t off = (size_t)(kb + 128) * N1_;
#pragma unroll
      for (int r = 0; r < 4; r++)
        gload_lds16(ksrc + off + (size_t)(8*r) * N1_, (char*)Ks + r*1024);
    }

    // ---- softmax + pack A ----
    if (kt == sA) {
#pragma unroll
      for (int r = 0; r < 16; r++) {
        int keyg = kb + (r&3) + 8*(r>>2) + 4*hi;
        if (keyg > qgA) stA[r] = -__builtin_inff();
      }
    }
    {
      float ts = 0.f;
#pragma unroll
      for (int r = 0; r < 16; r++) {
        float pp = exp2v(stA[r]);
        stA[r] = pp;
        ts += pp;
      }
      lA += ts;
    }
    bf16x8 pfA0, pfA1;
    {
      u32 pk[8];
#pragma unroll
      for (int m = 0; m < 8; m++) pk[m] = cvtpk(stA[2*m], stA[2*m+1]);
      asm volatile("v_permlane32_swap_b32 %0, %1" : "+v"(pk[0]), "+v"(pk[2]));
      asm volatile("v_permlane32_swap_b32 %0, %1" : "+v"(pk[1]), "+v"(pk[3]));
      asm volatile("v_permlane32_swap_b32 %0, %1" : "+v"(pk[4]), "+v"(pk[6]));
      asm volatile("v_permlane32_swap_b32 %0, %1" : "+v"(pk[5]), "+v"(pk[7]));
      u32x4 f0 = { pk[0], pk[1], pk[2], pk[3] };
      u32x4 f1 = { pk[4], pk[5], pk[6], pk[7] };
      pfA0 = __builtin_bit_cast(bf16x8, f0);
      pfA1 = __builtin_bit_cast(bf16x8, f1);
    }
    bf16x8 pfB0, pfB1;
    if (actB) {
      if (kt == sB) {
#pragma unroll
        for (int r = 0; r < 16; r++) {
          int keyg = kb + (r&3) + 8*(r>>2) + 4*hi;
          if (keyg > qgB) stB[r] = -__builtin_inff();
        }
      }
      {
        float ts = 0.f;
#pragma unroll
        for (int r = 0; r < 16; r++) {
          float pp = exp2v(stB[r]);
          stB[r] = pp;
          ts += pp;
        }
        lB += ts;
      }
      u32 pk[8];
#pragma unroll
      for (int m = 0; m < 8; m++) pk[m] = cvtpk(stB[2*m], stB[2*m+1]);
      asm volatile("v_permlane32_swap_b32 %0, %1" : "+v"(pk[0]), "+v"(pk[2]));
      asm volatile("v_permlane32_swap_b32 %0, %1" : "+v"(pk[1]), "+v"(pk[3]));
      asm volatile("v_permlane32_swap_b32 %0, %1" : "+v"(pk[4]), "+v"(pk[6]));
      asm volatile("v_permlane32_swap_b32 %0, %1" : "+v"(pk[5]), "+v"(pk[7]));
      u32x4 f0 = { pk[0], pk[1], pk[2], pk[3] };
      u32x4 f1 = { pk[4], pk[5], pk[6], pk[7] };
      pfB0 = __builtin_bit_cast(bf16x8, f0);
      pfB1 = __builtin_bit_cast(bf16x8, f1);
    }

    // ---- V(t) landed in LDS (K(t+4) may remain in flight) ----
    if (!lastown) asm volatile("s_waitcnt vmcnt(4)" ::: "memory");
    else          asm volatile("s_waitcnt vmcnt(0)" ::: "memory");

    // ---- PV: O^T += V^T * P^T; vf = 8x ds_read_u16 from linear V ----
    __builtin_amdgcn_s_setprio(1);
    if (actB) {
#pragma unroll
      for (int dt = 0; dt < 2; dt++)
#pragma unroll
        for (int ks = 0; ks < 2; ks++) {
          u16 tv[8];
#pragma unroll
          for (int jj = 0; jj < 8; jj++)
            tv[jj] = Vl[(16*ks + 8*hi + jj)*64 + 32*dt + q31];
          bf16x8 vf = *reinterpret_cast<const bf16x8*>(tv);
          oaccA[dt] = __builtin_amdgcn_mfma_f32_32x32x16_bf16(vf, ks ? pfA1 : pfA0, oaccA[dt], 0, 0, 0);
          oaccB[dt] = __builtin_amdgcn_mfma_f32_32x32x16_bf16(vf, ks ? pfB1 : pfB0, oaccB[dt], 0, 0, 0);
        }
    } else {
#pragma unroll
      for (int dt = 0; dt < 2; dt++)
#pragma unroll
        for (int ks = 0; ks < 2; ks++) {
          u16 tv[8];
#pragma unroll
          for (int jj = 0; jj < 8; jj++)
            tv[jj] = Vl[(16*ks + 8*hi + jj)*64 + 32*dt + q31];
          bf16x8 vf = *reinterpret_cast<const bf16x8*>(tv);
          oaccA[dt] = __builtin_amdgcn_mfma_f32_32x32x16_bf16(vf, ks ? pfA1 : pfA0, oaccA[dt], 0, 0, 0);
        }
    }
    __builtin_amdgcn_s_setprio(0);
    LGKM0();                      // Vl reads retired before V(t+4) prefetch

    // ---- prefetch V(t+4) into Vl ----
    if (!lastown) {
      size_t off = (size_t)(kb + 128) * N1_;
#pragma unroll
      for (int r = 0; r < 4; r++)
        gload_lds16(vsrc + off + (size_t)(8*r) * N1_, (char*)Vl + r*1024);
    }
  }
  lA += __shfl_xor(lA, 32);
  lB += __shfl_xor(lB, 32);

  // ---- merge strip A (4-way) ----
  __syncthreads();
  if (w) {
    float* park = (float*)Sm[w];
#pragma unroll
    for (int dt = 0; dt < 2; dt++)
#pragma unroll
      for (int r = 0; r < 16; r++) park[(dt*16 + r)*64 + lane] = oaccA[dt][r];
    float* ml = (float*)Sm[0];
    ml[(w-1)*64 + lane] = lA;
  }
  __syncthreads();
  if (w == 0) {
    const float* ml = (const float*)Sm[0];
    float linv = 1.f / (lA + ml[lane] + ml[64 + lane] + ml[128 + lane]);
    const float* p1 = (const float*)Sm[1];
    const float* p2 = (const float*)Sm[2];
    const float* p3 = (const float*)Sm[3];
    u16* orow = attnout + (size_t)(b*T_ + qgA) * C_ + h*HD_;
#pragma unroll
    for (int dt = 0; dt < 2; dt++)
#pragma unroll
      for (int m = 0; m < 8; m++) {
        int e0 = (dt*16 + 2*m)*64 + lane, e1 = e0 + 64;
        float v0 = (oaccA[dt][2*m]   + p1[e0] + p2[e0] + p3[e0]) * linv;
        float v1 = (oaccA[dt][2*m+1] + p1[e1] + p2[e1] + p3[e1]) * linv;
        int d = 32*dt + 2*(m&1) + 8*(m>>1) + 4*hi;
        *reinterpret_cast<u32*>(orow + d) = cvtpk(v0, v1);
      }
  }
  __syncthreads();
  // ---- merge strip B (4-way) ----
  if (w) {
    float* park = (float*)Sm[w];
#pragma unroll
    for (int dt = 0; dt < 2; dt++)
#pragma unroll
      for (int r = 0; r < 16; r++) park[(dt*16 + r)*64 + lane] = oaccB[dt][r];
    float* ml = (float*)Sm[0];
    ml[(w-1)*64 + lane] = lB;
  }
  __syncthreads();
  if (w == 0) {
    const float* ml = (const float*)Sm[0];
    float linv = 1.f / (lB + ml[lane] + ml[64 + lane] + ml[128 + lane]);
    const float* p1 = (const float*)Sm[1];
    const float* p2 = (const float*)Sm[2];
    const float* p3 = (const float*)Sm[3];
    u16* orow = attnout + (size_t)(b*T_ + qgB) * C_ + h*HD_;
#pragma unroll
    for (int dt = 0; dt < 2; dt++)
#pragma unroll
      for (int m = 0; m < 8; m++) {
        int e0 = (dt*16 + 2*m)*64 + lane, e1 = e0 + 64;
        float v0 = (oaccB[dt][2*m]   + p1[e0] + p2[e0] + p3[e0]) * linv;
        float v1 = (oaccB[dt][2*m+1] + p1[e1] + p2[e1] + p3[e1]) * linv;
        int d = 32*dt + 2*(m&1) + 8*(m>>1) + 4*hi;
        *reinterpret_cast<u32*>(orow + d) = cvtpk(v0, v1);
      }
  }
}

extern "C" void kernel_launch(void* const* d_in, const int* in_sizes, int n_in,
                              void* d_out, int out_size, void* d_ws, size_t ws_size,
                              hipStream_t stream) {
  const float* x     = (const float*)d_in[0];
  const float* w_qkv = (const float*)d_in[1];
  const float* w_out = (const float*)d_in[2];
  float* out = (float*)d_out;
  char* ws = (char*)d_ws;
  u16* xb    = (u16*)(ws);                         // 8 MB  : x bf16 (4096 x 1024)
  u16* wqkvT = (u16*)(ws + ((size_t)8  << 20));    // 6 MB  : w_qkv^T bf16 (3072 x 1024)
  u16* woutT = (u16*)(ws + ((size_t)14 << 20));    // 2 MB  : w_out^T bf16 (1024 x 1024)
  u16* qkvb  = (u16*)(ws + ((size_t)16 << 20));    // 24 MB : qkv bf16 (4096 x 3072)
  u16* attnb = (u16*)(ws + ((size_t)40 << 20));    // 8 MB  : attn out bf16 (4096 x 1024)

  prep_k<<<8192, 256, 0, stream>>>(x, w_qkv, w_out, xb, wqkvT, woutT);
  gemm256<<<dim3(16, 16), 512, 0, stream>>>(xb, wqkvT, qkvb);
  attn_kernel<<<1024, 256, 0, stream>>>(qkvb, attnb);
  gemm128<<<dim3(8, 32), 512, 0, stream>>>(attnb, woutT, out);
}

// Round 28
// 94.185 us; speedup vs baseline: 1.0427x; 1.0427x over previous
//
#include <hip/hip_runtime.h>
#include <hip/hip_bf16.h>
#include <stdint.h>
#include <math.h>

#define B_ 2
#define T_ 2048
#define C_ 1024
#define H_ 16
#define HD_ 64
#define BT_ (B_*T_)      // 4096 rows
#define N1_ (3*C_)       // 3072

typedef unsigned short u16;
typedef uint32_t u32;
typedef __attribute__((ext_vector_type(8))) short bf16x8;
typedef __attribute__((ext_vector_type(4))) float f32x4;
typedef __attribute__((ext_vector_type(16))) float f32x16;
typedef __attribute__((ext_vector_type(4))) unsigned int u32x4;

__device__ __forceinline__ u16 f2bf(float f) {
  __hip_bfloat16 h = __float2bfloat16(f);
  return *reinterpret_cast<u16*>(&h);
}
__device__ __forceinline__ float bf2f(u16 u) {
  u32 w = ((u32)u) << 16;
  return *reinterpret_cast<float*>(&w);
}
__device__ __forceinline__ u32 cvtpk(float lo, float hi) {
  u32 r;
  asm("v_cvt_pk_bf16_f32 %0, %1, %2" : "=v"(r) : "v"(lo), "v"(hi));
  return r;
}
__device__ __forceinline__ float exp2v(float x) {   // exact v_exp_f32 (2^x); -inf -> 0
  float r;
  asm("v_exp_f32 %0, %1" : "=v"(r) : "v"(x));
  return r;
}

__device__ __forceinline__ void gload_lds16(const void* g, void* l) {
  __builtin_amdgcn_global_load_lds(
      (const __attribute__((address_space(1))) uint32_t*)g,
      (__attribute__((address_space(3))) uint32_t*)l, 16, 0, 0);
}

// raw workgroup barrier WITHOUT __syncthreads' vmcnt(0) drain
#define BARX() do { asm volatile("" ::: "memory"); __builtin_amdgcn_s_barrier(); \
                    asm volatile("" ::: "memory"); } while (0)
// lgkm drain + scheduler fence (rule #18)
#define LGKM0() do { asm volatile("s_waitcnt lgkmcnt(0)" ::: "memory"); \
                     __builtin_amdgcn_sched_barrier(0); } while (0)

// ---------------- fused prep: cast x + transpose-cast both weights ----------------
__global__ __launch_bounds__(256) void prep_k(const float* __restrict__ x,
                                              const float* __restrict__ w_qkv,
                                              const float* __restrict__ w_out,
                                              u16* __restrict__ xb,
                                              u16* __restrict__ wqkvT,
                                              u16* __restrict__ woutT) {
  __shared__ float tile[32][33];
  int bid = blockIdx.x;
  if (bid < 4096) {
    int idx = bid * 1024 + threadIdx.x * 4;
    float4 v = *reinterpret_cast<const float4*>(x + idx);
    u16 tmp[4] = {f2bf(v.x), f2bf(v.y), f2bf(v.z), f2bf(v.w)};
    *reinterpret_cast<uint2*>(xb + idx) = *reinterpret_cast<const uint2*>(tmp);
    return;
  }
  const float* w;
  u16* wt;
  int N, tb;
  if (bid < 7168) { tb = bid - 4096; w = w_qkv; wt = wqkvT; N = N1_; }
  else            { tb = bid - 7168; w = w_out; wt = woutT; N = C_;  }
  int nx = N >> 5;
  int n0 = (tb % nx) * 32, k0 = (tb / nx) * 32;
  int tx = threadIdx.x & 31, ty = threadIdx.x >> 5;
#pragma unroll
  for (int i = 0; i < 4; i++)
    tile[ty + i*8][tx] = w[(size_t)(k0 + ty + i*8) * N + n0 + tx];
  __syncthreads();
#pragma unroll
  for (int i = 0; i < 4; i++)
    wt[(size_t)(n0 + ty + i*8) * 1024 + k0 + tx] = f2bf(tile[tx][ty + i*8]);
}

// ---------------- QKV GEMM: 256x192, BK=64, SINGLE-BARRIER tile schedule ----------------
// Per K-tile: vmcnt(0) cert + BARX (transitively certifies ALL waves' stages for t
// and all t-1 reads done) -> read all 22 b128 frags | stage t+1 (7 gloads) ->
// lgkm drain -> 48 MFMA (setprio). 1 barrier/tile (was 3); waves desync within the
// tile so one wave's reads overlap the other's MFMA block.
__global__ __launch_bounds__(512, 2) void gemm256(const u16* __restrict__ A, const u16* __restrict__ Bt,
                                                  u16* __restrict__ Cc) {
  __shared__ u16 As[2][256*64];
  __shared__ u16 Bs[2][192*64];
  int tid = threadIdx.x, w = tid >> 6, lane = tid & 63;
  int m0 = blockIdx.y * 256, n0 = blockIdx.x * 192;
  int wm = (w >> 2) * 128, wn = (w & 3) * 48;
  f32x4 acc[8][3] = {};

  size_t aoff[4];
  size_t boff[3];
#pragma unroll
  for (int i = 0; i < 4; i++) {
    int c = i*512 + tid, row = c >> 3;
    aoff[i] = (size_t)(m0 + row) * 1024 + (size_t)((((c & 7) ^ (row & 7))) * 8);
  }
#pragma unroll
  for (int i = 0; i < 3; i++) {
    int c = i*512 + tid, row = c >> 3;
    boff[i] = (size_t)(n0 + row) * 1024 + (size_t)((((c & 7) ^ (row & 7))) * 8);
  }
  int dstc = w * 1024;

  int r15 = lane & 15, kq = lane >> 4;
  int slot0 = (kq ^ (r15 & 7)) * 8;
  int abase = (wm + r15) * 64;
  int bbase = (wn + r15) * 64;

#pragma unroll
  for (int i = 0; i < 4; i++)
    gload_lds16(A + aoff[i], (char*)&As[0][0] + i*8192 + dstc);
#pragma unroll
  for (int i = 0; i < 3; i++)
    gload_lds16(Bt + boff[i], (char*)&Bs[0][0] + i*8192 + dstc);

  for (int t = 0; t < 16; ++t) {
    int buf = t & 1;
    const u16* Ab = &As[buf][0];
    const u16* Bb = &Bs[buf][0];
    int slot1 = slot0 ^ 32;
    bf16x8 a0[8], a1[8], b0[3], b1[3];

    // cert: my stages for t landed; barrier makes it true for ALL waves, and all
    // waves' reads of buf^1 (tile t-1) are complete -> staging buf^1 is safe.
    asm volatile("s_waitcnt vmcnt(0)" ::: "memory");
    BARX();

    // reads (both k-slots) hoisted; stage t+1 under them
#pragma unroll
    for (int nf = 0; nf < 3; nf++) {
      b0[nf] = *reinterpret_cast<const bf16x8*>(&Bb[bbase + nf*1024 + slot0]);
      b1[nf] = *reinterpret_cast<const bf16x8*>(&Bb[bbase + nf*1024 + slot1]);
    }
#pragma unroll
    for (int mf = 0; mf < 8; mf++) {
      a0[mf] = *reinterpret_cast<const bf16x8*>(&Ab[abase + mf*1024 + slot0]);
      a1[mf] = *reinterpret_cast<const bf16x8*>(&Ab[abase + mf*1024 + slot1]);
    }
    if (t < 15) {
      int ko = (t + 1) * 64;
#pragma unroll
      for (int i = 0; i < 4; i++)
        gload_lds16(A + aoff[i] + ko, (char*)&As[buf ^ 1][0] + i*8192 + dstc);
#pragma unroll
      for (int i = 0; i < 3; i++)
        gload_lds16(Bt + boff[i] + ko, (char*)&Bs[buf ^ 1][0] + i*8192 + dstc);
    }
    LGKM0();
    __builtin_amdgcn_s_setprio(1);
#pragma unroll
    for (int mf = 0; mf < 8; mf++)
#pragma unroll
      for (int nf = 0; nf < 3; nf++)
        acc[mf][nf] = __builtin_amdgcn_mfma_f32_16x16x32_bf16(a0[mf], b0[nf], acc[mf][nf], 0, 0, 0);
#pragma unroll
    for (int mf = 0; mf < 8; mf++)
#pragma unroll
      for (int nf = 0; nf < 3; nf++)
        acc[mf][nf] = __builtin_amdgcn_mfma_f32_16x16x32_bf16(a1[mf], b1[nf], acc[mf][nf], 0, 0, 0);
    __builtin_amdgcn_s_setprio(0);
  }

  int rg = kq * 4;
#pragma unroll
  for (int mf = 0; mf < 8; mf++)
#pragma unroll
    for (int nf = 0; nf < 3; nf++) {
      size_t basei = (size_t)(m0 + wm + mf*16 + rg) * N1_ + (size_t)(n0 + wn + nf*16 + r15);
#pragma unroll
      for (int r = 0; r < 4; r++)
        Cc[basei + (size_t)r * N1_] = f2bf(acc[mf][nf][r]);
    }
}

// ---------------- out-proj GEMM: 128x128, BK=64, 8 waves (R22-proven) ----------------
__global__ __launch_bounds__(512, 1) void gemm128(const u16* __restrict__ A, const u16* __restrict__ Bt,
                                                  float* __restrict__ Co) {
  __shared__ u16 As[2][128*64];
  __shared__ u16 Bs[2][128*64];
  int tid = threadIdx.x, w = tid >> 6, lane = tid & 63;
  int m0 = blockIdx.y * 128, n0 = blockIdx.x * 128;
  int wm = (w >> 2) * 64, wn = (w & 3) * 32;
  f32x4 acc[4][2] = {};

  size_t aoff[2], boff[2];
#pragma unroll
  for (int i = 0; i < 2; i++) {
    int c = i*512 + tid, row = c >> 3;
    aoff[i] = (size_t)(m0 + row) * 1024 + (size_t)((((c & 7) ^ (row & 7))) * 8);
    boff[i] = (size_t)(n0 + row) * 1024 + (size_t)((((c & 7) ^ (row & 7))) * 8);
  }
  int dstc = w * 1024;

  int r15 = lane & 15, kq = lane >> 4;
  int slot0 = (kq ^ (r15 & 7)) * 8;
  int abase = (wm + r15) * 64;
  int bbase = (wn + r15) * 64;

#pragma unroll
  for (int i = 0; i < 2; i++) {
    gload_lds16(A  + aoff[i], (char*)&As[0][0] + i*8192 + dstc);
    gload_lds16(Bt + boff[i], (char*)&Bs[0][0] + i*8192 + dstc);
  }

  for (int t = 0; t < 16; ++t) {
    int buf = t & 1;
    const u16* Ab = &As[buf][0];
    const u16* Bb = &Bs[buf][0];
    int slot1 = slot0 ^ 32;
    bf16x8 af[4], bfv[2];

    asm volatile("s_waitcnt vmcnt(0)" ::: "memory");
    BARX();

#pragma unroll
    for (int nf = 0; nf < 2; nf++) bfv[nf] = *reinterpret_cast<const bf16x8*>(&Bb[bbase + nf*1024 + slot0]);
#pragma unroll
    for (int mf = 0; mf < 4; mf++) af[mf] = *reinterpret_cast<const bf16x8*>(&Ab[abase + mf*1024 + slot0]);
    if (t < 15) {
      int ko = (t + 1) * 64;
#pragma unroll
      for (int i = 0; i < 2; i++) {
        gload_lds16(A  + aoff[i] + ko, (char*)&As[buf ^ 1][0] + i*8192 + dstc);
        gload_lds16(Bt + boff[i] + ko, (char*)&Bs[buf ^ 1][0] + i*8192 + dstc);
      }
    }
    BARX();
    LGKM0();
    __builtin_amdgcn_s_setprio(1);
#pragma unroll
    for (int mf = 0; mf < 4; mf++)
#pragma unroll
      for (int nf = 0; nf < 2; nf++)
        acc[mf][nf] = __builtin_amdgcn_mfma_f32_16x16x32_bf16(af[mf], bfv[nf], acc[mf][nf], 0, 0, 0);
    __builtin_amdgcn_s_setprio(0);

#pragma unroll
    for (int nf = 0; nf < 2; nf++) bfv[nf] = *reinterpret_cast<const bf16x8*>(&Bb[bbase + nf*1024 + slot1]);
#pragma unroll
    for (int mf = 0; mf < 4; mf++) af[mf] = *reinterpret_cast<const bf16x8*>(&Ab[abase + mf*1024 + slot1]);
    BARX();
    LGKM0();
    __builtin_amdgcn_s_setprio(1);
#pragma unroll
    for (int mf = 0; mf < 4; mf++)
#pragma unroll
      for (int nf = 0; nf < 2; nf++)
        acc[mf][nf] = __builtin_amdgcn_mfma_f32_16x16x32_bf16(af[mf], bfv[nf], acc[mf][nf], 0, 0, 0);
    __builtin_amdgcn_s_setprio(0);
  }

  int rg = kq * 4;
#pragma unroll
  for (int mf = 0; mf < 4; mf++)
#pragma unroll
    for (int nf = 0; nf < 2; nf++) {
      size_t basei = (size_t)(m0 + wm + mf*16 + rg) * C_ + (size_t)(n0 + wn + nf*16 + r15);
#pragma unroll
      for (int r = 0; r < 4; r++)
        Co[basei + (size_t)r * C_] = acc[mf][nf][r];
    }
}

// ---------------- causal flash attention: R26 exact (best proven, ~41us) ----------------
__global__ __launch_bounds__(256, 2) void attn_kernel(const u16* __restrict__ qkv, u16* __restrict__ attnout) {
  __shared__ u16 Sm[4][4096];    // per wave: K tile [0..2047], V tile linear [2048..4095]
  int tid = threadIdx.x;
  int w = tid >> 6, lane = tid & 63;
  int q31 = lane & 31, hi = lane >> 5;
  int lid = blockIdx.x;
  int xcd = lid & 7, j = lid >> 3;
  int bh = xcd * 4 + (j & 3);
  int p = j >> 2;                // 0..31
  int b = bh >> 4, h = bh & 15;
  const u16* base = qkv + (size_t)b * T_ * N1_;

  u16* Ks = Sm[w];
  u16* Vl = Sm[w] + 2048;

  const u16* ksrc = base + C_ + h*HD_ + (size_t)(lane >> 3) * N1_
                    + (size_t)(((lane & 7) ^ ((lane >> 3) & 7)) * 8);
  const u16* vsrc = base + 2*C_ + h*HD_ + (size_t)(lane >> 3) * N1_
                    + (size_t)((lane & 7) * 8);
  const float QSC = 0.125f * 1.44269504088896f;

  int sA = 63 - p, sB = p;
  int qgA = sA * 32 + q31, qgB = sB * 32 + q31;
  int nktU = sA + 1;             // >= 33, all 4 waves active

  bf16x8 qfA[4], qfB[4];
  {
    const u16* qrowA = base + (size_t)qgA * N1_ + h * HD_;
    const u16* qrowB = base + (size_t)qgB * N1_ + h * HD_;
#pragma unroll
    for (int kk = 0; kk < 4; kk++) {
      bf16x8 ra = *reinterpret_cast<const bf16x8*>(qrowA + kk*16 + hi*8);
      bf16x8 rb = *reinterpret_cast<const bf16x8*>(qrowB + kk*16 + hi*8);
      const u16* pa = (const u16*)&ra;
      const u16* pb = (const u16*)&rb;
      u32x4 qa, qb;
#pragma unroll
      for (int jj = 0; jj < 4; jj++) {
        qa[jj] = cvtpk(bf2f(pa[2*jj]) * QSC, bf2f(pa[2*jj+1]) * QSC);
        qb[jj] = cvtpk(bf2f(pb[2*jj]) * QSC, bf2f(pb[2*jj+1]) * QSC);
      }
      qfA[kk] = __builtin_bit_cast(bf16x8, qa);
      qfB[kk] = __builtin_bit_cast(bf16x8, qb);
    }
  }

  f32x16 oaccA[2] = {}, oaccB[2] = {};
  float lA = 0.f, lB = 0.f;

  // ---- prologue: stage K(w) then V(w) via gload_lds (8 outstanding) ----
  {
    size_t off0 = (size_t)(w * 32) * N1_;
#pragma unroll
    for (int r = 0; r < 4; r++)
      gload_lds16(ksrc + off0 + (size_t)(8*r) * N1_, (char*)Ks + r*1024);
#pragma unroll
    for (int r = 0; r < 4; r++)
      gload_lds16(vsrc + off0 + (size_t)(8*r) * N1_, (char*)Vl + r*1024);
  }

  for (int kt = w; kt < nktU; kt += 4) {
    int kb = kt * 32;
    bool lastown = (kt + 4 >= nktU);
    bool actB = (kt <= sB);

    // ---- K(t) landed (V(t) + any K(t+4) remain countable) ----
    asm volatile("s_waitcnt vmcnt(4)" ::: "memory");

    // ---- QK^T (kf read once, both strips) ----
    f32x16 stA = {}, stB = {};
    if (actB) {
#pragma unroll
      for (int kk = 0; kk < 4; kk++) {
        bf16x8 kf = *reinterpret_cast<const bf16x8*>(
            &Ks[q31*64 + ((((kk<<1) | hi) ^ (q31 & 7)) << 3)]);
        stA = __builtin_amdgcn_mfma_f32_32x32x16_bf16(kf, qfA[kk], stA, 0, 0, 0);
        stB = __builtin_amdgcn_mfma_f32_32x32x16_bf16(kf, qfB[kk], stB, 0, 0, 0);
      }
    } else {
#pragma unroll
      for (int kk = 0; kk < 4; kk++) {
        bf16x8 kf = *reinterpret_cast<const bf16x8*>(
            &Ks[q31*64 + ((((kk<<1) | hi) ^ (q31 & 7)) << 3)]);
        stA = __builtin_amdgcn_mfma_f32_32x32x16_bf16(kf, qfA[kk], stA, 0, 0, 0);
      }
    }
    asm volatile("s_waitcnt lgkmcnt(0)" ::: "memory");   // Ks reads retired
    __builtin_amdgcn_sched_barrier(0);

    // ---- prefetch K(t+4) into Ks (safe: QK reads drained) ----
    if (!lastown) {
      size_t off = (size_t)(kb + 128) * N1_;
#pragma unroll
      for (int r = 0; r < 4; r++)
        gload_lds16(ksrc + off + (size_t)(8*r) * N1_, (char*)Ks + r*1024);
    }

    // ---- softmax + pack A ----
    if (kt == sA) {
#pragma unroll
      for (int r = 0; r < 16; r++) {
        int keyg = kb + (r&3) + 8*(r>>2) + 4*hi;
        if (keyg > qgA) stA[r] = -__builtin_inff();
      }
    }
    {
      float ts = 0.f;
#pragma unroll
      for (int r = 0; r < 16; r++) {
        float pp = exp2v(stA[r]);
        stA[r] = pp;
        ts += pp;
      }
      lA += ts;
    }
    bf16x8 pfA0, pfA1;
    {
      u32 pk[8];
#pragma unroll
      for (int m = 0; m < 8; m++) pk[m] = cvtpk(stA[2*m], stA[2*m+1]);
      asm volatile("v_permlane32_swap_b32 %0, %1" : "+v"(pk[0]), "+v"(pk[2]));
      asm volatile("v_permlane32_swap_b32 %0, %1" : "+v"(pk[1]), "+v"(pk[3]));
      asm volatile("v_permlane32_swap_b32 %0, %1" : "+v"(pk[4]), "+v"(pk[6]));
      asm volatile("v_permlane32_swap_b32 %0, %1" : "+v"(pk[5]), "+v"(pk[7]));
      u32x4 f0 = { pk[0], pk[1], pk[2], pk[3] };
      u32x4 f1 = { pk[4], pk[5], pk[6], pk[7] };
      pfA0 = __builtin_bit_cast(bf16x8, f0);
      pfA1 = __builtin_bit_cast(bf16x8, f1);
    }
    bf16x8 pfB0, pfB1;
    if (actB) {
      if (kt == sB) {
#pragma unroll
        for (int r = 0; r < 16; r++) {
          int keyg = kb + (r&3) + 8*(r>>2) + 4*hi;
          if (keyg > qgB) stB[r] = -__builtin_inff();
        }
      }
      {
        float ts = 0.f;
#pragma unroll
        for (int r = 0; r < 16; r++) {
          float pp = exp2v(stB[r]);
          stB[r] = pp;
          ts += pp;
        }
        lB += ts;
      }
      u32 pk[8];
#pragma unroll
      for (int m = 0; m < 8; m++) pk[m] = cvtpk(stB[2*m], stB[2*m+1]);
      asm volatile("v_permlane32_swap_b32 %0, %1" : "+v"(pk[0]), "+v"(pk[2]));
      asm volatile("v_permlane32_swap_b32 %0, %1" : "+v"(pk[1]), "+v"(pk[3]));
      asm volatile("v_permlane32_swap_b32 %0, %1" : "+v"(pk[4]), "+v"(pk[6]));
      asm volatile("v_permlane32_swap_b32 %0, %1" : "+v"(pk[5]), "+v"(pk[7]));
      u32x4 f0 = { pk[0], pk[1], pk[2], pk[3] };
      u32x4 f1 = { pk[4], pk[5], pk[6], pk[7] };
      pfB0 = __builtin_bit_cast(bf16x8, f0);
      pfB1 = __builtin_bit_cast(bf16x8, f1);
    }

    // ---- V(t) landed in LDS (K(t+4) may remain in flight) ----
    if (!lastown) asm volatile("s_waitcnt vmcnt(4)" ::: "memory");
    else          asm volatile("s_waitcnt vmcnt(0)" ::: "memory");

    // ---- PV: O^T += V^T * P^T; vf = 8x ds_read_u16 from linear V ----
    if (actB) {
#pragma unroll
      for (int dt = 0; dt < 2; dt++)
#pragma unroll
        for (int ks = 0; ks < 2; ks++) {
          u16 tv[8];
#pragma unroll
          for (int jj = 0; jj < 8; jj++)
            tv[jj] = Vl[(16*ks + 8*hi + jj)*64 + 32*dt + q31];
          bf16x8 vf = *reinterpret_cast<const bf16x8*>(tv);
          oaccA[dt] = __builtin_amdgcn_mfma_f32_32x32x16_bf16(vf, ks ? pfA1 : pfA0, oaccA[dt], 0, 0, 0);
          oaccB[dt] = __builtin_amdgcn_mfma_f32_32x32x16_bf16(vf, ks ? pfB1 : pfB0, oaccB[dt], 0, 0, 0);
        }
    } else {
#pragma unroll
      for (int dt = 0; dt < 2; dt++)
#pragma unroll
        for (int ks = 0; ks < 2; ks++) {
          u16 tv[8];
#pragma unroll
          for (int jj = 0; jj < 8; jj++)
            tv[jj] = Vl[(16*ks + 8*hi + jj)*64 + 32*dt + q31];
          bf16x8 vf = *reinterpret_cast<const bf16x8*>(tv);
          oaccA[dt] = __builtin_amdgcn_mfma_f32_32x32x16_bf16(vf, ks ? pfA1 : pfA0, oaccA[dt], 0, 0, 0);
        }
    }
    LGKM0();                      // Vl reads retired before V(t+4) prefetch

    // ---- prefetch V(t+4) into Vl ----
    if (!lastown) {
      size_t off = (size_t)(kb + 128) * N1_;
#pragma unroll
      for (int r = 0; r < 4; r++)
        gload_lds16(vsrc + off + (size_t)(8*r) * N1_, (char*)Vl + r*1024);
    }
  }
  lA += __shfl_xor(lA, 32);
  lB += __shfl_xor(lB, 32);

  // ---- merge strip A (4-way) ----
  __syncthreads();
  if (w) {
    float* park = (float*)Sm[w];
#pragma unroll
    for (int dt = 0; dt < 2; dt++)
#pragma unroll
      for (int r = 0; r < 16; r++) park[(dt*16 + r)*64 + lane] = oaccA[dt][r];
    float* ml = (float*)Sm[0];
    ml[(w-1)*64 + lane] = lA;
  }
  __syncthreads();
  if (w == 0) {
    const float* ml = (const float*)Sm[0];
    float linv = 1.f / (lA + ml[lane] + ml[64 + lane] + ml[128 + lane]);
    const float* p1 = (const float*)Sm[1];
    const float* p2 = (const float*)Sm[2];
    const float* p3 = (const float*)Sm[3];
    u16* orow = attnout + (size_t)(b*T_ + qgA) * C_ + h*HD_;
#pragma unroll
    for (int dt = 0; dt < 2; dt++)
#pragma unroll
      for (int m = 0; m < 8; m++) {
        int e0 = (dt*16 + 2*m)*64 + lane, e1 = e0 + 64;
        float v0 = (oaccA[dt][2*m]   + p1[e0] + p2[e0] + p3[e0]) * linv;
        float v1 = (oaccA[dt][2*m+1] + p1[e1] + p2[e1] + p3[e1]) * linv;
        int d = 32*dt + 2*(m&1) + 8*(m>>1) + 4*hi;
        *reinterpret_cast<u32*>(orow + d) = cvtpk(v0, v1);
      }
  }
  __syncthreads();
  // ---- merge strip B (4-way) ----
  if (w) {
    float* park = (float*)Sm[w];
#pragma unroll
    for (int dt = 0; dt < 2; dt++)
#pragma unroll
      for (int r = 0; r < 16; r++) park[(dt*16 + r)*64 + lane] = oaccB[dt][r];
    float* ml = (float*)Sm[0];
    ml[(w-1)*64 + lane] = lB;
  }
  __syncthreads();
  if (w == 0) {
    const float* ml = (const float*)Sm[0];
    float linv = 1.f / (lB + ml[lane] + ml[64 + lane] + ml[128 + lane]);
    const float* p1 = (const float*)Sm[1];
    const float* p2 = (const float*)Sm[2];
    const float* p3 = (const float*)Sm[3];
    u16* orow = attnout + (size_t)(b*T_ + qgB) * C_ + h*HD_;
#pragma unroll
    for (int dt = 0; dt < 2; dt++)
#pragma unroll
      for (int m = 0; m < 8; m++) {
        int e0 = (dt*16 + 2*m)*64 + lane, e1 = e0 + 64;
        float v0 = (oaccB[dt][2*m]   + p1[e0] + p2[e0] + p3[e0]) * linv;
        float v1 = (oaccB[dt][2*m+1] + p1[e1] + p2[e1] + p3[e1]) * linv;
        int d = 32*dt + 2*(m&1) + 8*(m>>1) + 4*hi;
        *reinterpret_cast<u32*>(orow + d) = cvtpk(v0, v1);
      }
  }
}

extern "C" void kernel_launch(void* const* d_in, const int* in_sizes, int n_in,
                              void* d_out, int out_size, void* d_ws, size_t ws_size,
                              hipStream_t stream) {
  const float* x     = (const float*)d_in[0];
  const float* w_qkv = (const float*)d_in[1];
  const float* w_out = (const float*)d_in[2];
  float* out = (float*)d_out;
  char* ws = (char*)d_ws;
  u16* xb    = (u16*)(ws);                         // 8 MB  : x bf16 (4096 x 1024)
  u16* wqkvT = (u16*)(ws + ((size_t)8  << 20));    // 6 MB  : w_qkv^T bf16 (3072 x 1024)
  u16* woutT = (u16*)(ws + ((size_t)14 << 20));    // 2 MB  : w_out^T bf16 (1024 x 1024)
  u16* qkvb  = (u16*)(ws + ((size_t)16 << 20));    // 24 MB : qkv bf16 (4096 x 3072)
  u16* attnb = (u16*)(ws + ((size_t)40 << 20));    // 8 MB  : attn out bf16 (4096 x 1024)

  prep_k<<<8192, 256, 0, stream>>>(x, w_qkv, w_out, xb, wqkvT, woutT);
  gemm256<<<dim3(16, 16), 512, 0, stream>>>(xb, wqkvT, qkvb);
  attn_kernel<<<1024, 256, 0, stream>>>(qkvb, attnb);
  gemm128<<<dim3(8, 32), 512, 0, stream>>>(attnb, woutT, out);
}

// Round 29
// 92.211 us; speedup vs baseline: 1.0650x; 1.0214x over previous
//
#include <hip/hip_runtime.h>
#include <hip/hip_bf16.h>
#include <stdint.h>
#include <math.h>

#define B_ 2
#define T_ 2048
#define C_ 1024
#define H_ 16
#define HD_ 64
#define BT_ (B_*T_)      // 4096 rows
#define N1_ (3*C_)       // 3072

typedef unsigned short u16;
typedef uint32_t u32;
typedef __attribute__((ext_vector_type(8))) short bf16x8;
typedef __attribute__((ext_vector_type(4))) float f32x4;
typedef __attribute__((ext_vector_type(16))) float f32x16;
typedef __attribute__((ext_vector_type(4))) unsigned int u32x4;

__device__ __forceinline__ u16 f2bf(float f) {
  __hip_bfloat16 h = __float2bfloat16(f);
  return *reinterpret_cast<u16*>(&h);
}
__device__ __forceinline__ float bf2f(u16 u) {
  u32 w = ((u32)u) << 16;
  return *reinterpret_cast<float*>(&w);
}
__device__ __forceinline__ u32 cvtpk(float lo, float hi) {
  u32 r;
  asm("v_cvt_pk_bf16_f32 %0, %1, %2" : "=v"(r) : "v"(lo), "v"(hi));
  return r;
}
__device__ __forceinline__ float exp2v(float x) {   // exact v_exp_f32 (2^x); -inf -> 0
  float r;
  asm("v_exp_f32 %0, %1" : "=v"(r) : "v"(x));
  return r;
}

__device__ __forceinline__ void gload_lds16(const void* g, void* l) {
  __builtin_amdgcn_global_load_lds(
      (const __attribute__((address_space(1))) uint32_t*)g,
      (__attribute__((address_space(3))) uint32_t*)l, 16, 0, 0);
}

// raw workgroup barrier WITHOUT __syncthreads' vmcnt(0) drain
#define BARX() do { asm volatile("" ::: "memory"); __builtin_amdgcn_s_barrier(); \
                    asm volatile("" ::: "memory"); } while (0)
// lgkm drain + scheduler fence (rule #18)
#define LGKM0() do { asm volatile("s_waitcnt lgkmcnt(0)" ::: "memory"); \
                     __builtin_amdgcn_sched_barrier(0); } while (0)

// ---------------- fused prep: cast x + transpose-cast both weights ----------------
__global__ __launch_bounds__(256) void prep_k(const float* __restrict__ x,
                                              const float* __restrict__ w_qkv,
                                              const float* __restrict__ w_out,
                                              u16* __restrict__ xb,
                                              u16* __restrict__ wqkvT,
                                              u16* __restrict__ woutT) {
  __shared__ float tile[32][33];
  int bid = blockIdx.x;
  if (bid < 4096) {
    int idx = bid * 1024 + threadIdx.x * 4;
    float4 v = *reinterpret_cast<const float4*>(x + idx);
    u16 tmp[4] = {f2bf(v.x), f2bf(v.y), f2bf(v.z), f2bf(v.w)};
    *reinterpret_cast<uint2*>(xb + idx) = *reinterpret_cast<const uint2*>(tmp);
    return;
  }
  const float* w;
  u16* wt;
  int N, tb;
  if (bid < 7168) { tb = bid - 4096; w = w_qkv; wt = wqkvT; N = N1_; }
  else            { tb = bid - 7168; w = w_out; wt = woutT; N = C_;  }
  int nx = N >> 5;
  int n0 = (tb % nx) * 32, k0 = (tb / nx) * 32;
  int tx = threadIdx.x & 31, ty = threadIdx.x >> 5;
#pragma unroll
  for (int i = 0; i < 4; i++)
    tile[ty + i*8][tx] = w[(size_t)(k0 + ty + i*8) * N + n0 + tx];
  __syncthreads();
#pragma unroll
  for (int i = 0; i < 4; i++)
    wt[(size_t)(n0 + ty + i*8) * 1024 + k0 + tx] = f2bf(tile[tx][ty + i*8]);
}

// ---------------- QKV GEMM: 256x192, BK=64, SINGLE-BARRIER tile schedule (R28-proven) ----------------
__global__ __launch_bounds__(512, 2) void gemm256(const u16* __restrict__ A, const u16* __restrict__ Bt,
                                                  u16* __restrict__ Cc) {
  __shared__ u16 As[2][256*64];
  __shared__ u16 Bs[2][192*64];
  int tid = threadIdx.x, w = tid >> 6, lane = tid & 63;
  int m0 = blockIdx.y * 256, n0 = blockIdx.x * 192;
  int wm = (w >> 2) * 128, wn = (w & 3) * 48;
  f32x4 acc[8][3] = {};

  size_t aoff[4];
  size_t boff[3];
#pragma unroll
  for (int i = 0; i < 4; i++) {
    int c = i*512 + tid, row = c >> 3;
    aoff[i] = (size_t)(m0 + row) * 1024 + (size_t)((((c & 7) ^ (row & 7))) * 8);
  }
#pragma unroll
  for (int i = 0; i < 3; i++) {
    int c = i*512 + tid, row = c >> 3;
    boff[i] = (size_t)(n0 + row) * 1024 + (size_t)((((c & 7) ^ (row & 7))) * 8);
  }
  int dstc = w * 1024;

  int r15 = lane & 15, kq = lane >> 4;
  int slot0 = (kq ^ (r15 & 7)) * 8;
  int abase = (wm + r15) * 64;
  int bbase = (wn + r15) * 64;

#pragma unroll
  for (int i = 0; i < 4; i++)
    gload_lds16(A + aoff[i], (char*)&As[0][0] + i*8192 + dstc);
#pragma unroll
  for (int i = 0; i < 3; i++)
    gload_lds16(Bt + boff[i], (char*)&Bs[0][0] + i*8192 + dstc);

  for (int t = 0; t < 16; ++t) {
    int buf = t & 1;
    const u16* Ab = &As[buf][0];
    const u16* Bb = &Bs[buf][0];
    int slot1 = slot0 ^ 32;
    bf16x8 a0[8], a1[8], b0[3], b1[3];

    asm volatile("s_waitcnt vmcnt(0)" ::: "memory");
    BARX();

#pragma unroll
    for (int nf = 0; nf < 3; nf++) {
      b0[nf] = *reinterpret_cast<const bf16x8*>(&Bb[bbase + nf*1024 + slot0]);
      b1[nf] = *reinterpret_cast<const bf16x8*>(&Bb[bbase + nf*1024 + slot1]);
    }
#pragma unroll
    for (int mf = 0; mf < 8; mf++) {
      a0[mf] = *reinterpret_cast<const bf16x8*>(&Ab[abase + mf*1024 + slot0]);
      a1[mf] = *reinterpret_cast<const bf16x8*>(&Ab[abase + mf*1024 + slot1]);
    }
    if (t < 15) {
      int ko = (t + 1) * 64;
#pragma unroll
      for (int i = 0; i < 4; i++)
        gload_lds16(A + aoff[i] + ko, (char*)&As[buf ^ 1][0] + i*8192 + dstc);
#pragma unroll
      for (int i = 0; i < 3; i++)
        gload_lds16(Bt + boff[i] + ko, (char*)&Bs[buf ^ 1][0] + i*8192 + dstc);
    }
    LGKM0();
    __builtin_amdgcn_s_setprio(1);
#pragma unroll
    for (int mf = 0; mf < 8; mf++)
#pragma unroll
      for (int nf = 0; nf < 3; nf++)
        acc[mf][nf] = __builtin_amdgcn_mfma_f32_16x16x32_bf16(a0[mf], b0[nf], acc[mf][nf], 0, 0, 0);
#pragma unroll
    for (int mf = 0; mf < 8; mf++)
#pragma unroll
      for (int nf = 0; nf < 3; nf++)
        acc[mf][nf] = __builtin_amdgcn_mfma_f32_16x16x32_bf16(a1[mf], b1[nf], acc[mf][nf], 0, 0, 0);
    __builtin_amdgcn_s_setprio(0);
  }

  int rg = kq * 4;
#pragma unroll
  for (int mf = 0; mf < 8; mf++)
#pragma unroll
    for (int nf = 0; nf < 3; nf++) {
      size_t basei = (size_t)(m0 + wm + mf*16 + rg) * N1_ + (size_t)(n0 + wn + nf*16 + r15);
#pragma unroll
      for (int r = 0; r < 4; r++)
        Cc[basei + (size_t)r * N1_] = f2bf(acc[mf][nf][r]);
    }
}

// ---------------- out-proj GEMM: 128x128, BK=64, SINGLE-BARRIER tile schedule ----------------
// Per K-tile: vmcnt(0) cert + BARX -> read all 12 b128 frags | stage t+1 (4 gloads)
// -> lgkm drain -> 16 MFMA (setprio). Same transitive-cert argument as gemm256.
__global__ __launch_bounds__(512, 1) void gemm128(const u16* __restrict__ A, const u16* __restrict__ Bt,
                                                  float* __restrict__ Co) {
  __shared__ u16 As[2][128*64];
  __shared__ u16 Bs[2][128*64];
  int tid = threadIdx.x, w = tid >> 6, lane = tid & 63;
  int m0 = blockIdx.y * 128, n0 = blockIdx.x * 128;
  int wm = (w >> 2) * 64, wn = (w & 3) * 32;
  f32x4 acc[4][2] = {};

  size_t aoff[2], boff[2];
#pragma unroll
  for (int i = 0; i < 2; i++) {
    int c = i*512 + tid, row = c >> 3;
    aoff[i] = (size_t)(m0 + row) * 1024 + (size_t)((((c & 7) ^ (row & 7))) * 8);
    boff[i] = (size_t)(n0 + row) * 1024 + (size_t)((((c & 7) ^ (row & 7))) * 8);
  }
  int dstc = w * 1024;

  int r15 = lane & 15, kq = lane >> 4;
  int slot0 = (kq ^ (r15 & 7)) * 8;
  int abase = (wm + r15) * 64;
  int bbase = (wn + r15) * 64;

#pragma unroll
  for (int i = 0; i < 2; i++) {
    gload_lds16(A  + aoff[i], (char*)&As[0][0] + i*8192 + dstc);
    gload_lds16(Bt + boff[i], (char*)&Bs[0][0] + i*8192 + dstc);
  }

  for (int t = 0; t < 16; ++t) {
    int buf = t & 1;
    const u16* Ab = &As[buf][0];
    const u16* Bb = &Bs[buf][0];
    int slot1 = slot0 ^ 32;
    bf16x8 a0[4], a1[4], b0[2], b1[2];

    asm volatile("s_waitcnt vmcnt(0)" ::: "memory");
    BARX();

#pragma unroll
    for (int nf = 0; nf < 2; nf++) {
      b0[nf] = *reinterpret_cast<const bf16x8*>(&Bb[bbase + nf*1024 + slot0]);
      b1[nf] = *reinterpret_cast<const bf16x8*>(&Bb[bbase + nf*1024 + slot1]);
    }
#pragma unroll
    for (int mf = 0; mf < 4; mf++) {
      a0[mf] = *reinterpret_cast<const bf16x8*>(&Ab[abase + mf*1024 + slot0]);
      a1[mf] = *reinterpret_cast<const bf16x8*>(&Ab[abase + mf*1024 + slot1]);
    }
    if (t < 15) {
      int ko = (t + 1) * 64;
#pragma unroll
      for (int i = 0; i < 2; i++) {
        gload_lds16(A  + aoff[i] + ko, (char*)&As[buf ^ 1][0] + i*8192 + dstc);
        gload_lds16(Bt + boff[i] + ko, (char*)&Bs[buf ^ 1][0] + i*8192 + dstc);
      }
    }
    LGKM0();
    __builtin_amdgcn_s_setprio(1);
#pragma unroll
    for (int mf = 0; mf < 4; mf++)
#pragma unroll
      for (int nf = 0; nf < 2; nf++)
        acc[mf][nf] = __builtin_amdgcn_mfma_f32_16x16x32_bf16(a0[mf], b0[nf], acc[mf][nf], 0, 0, 0);
#pragma unroll
    for (int mf = 0; mf < 4; mf++)
#pragma unroll
      for (int nf = 0; nf < 2; nf++)
        acc[mf][nf] = __builtin_amdgcn_mfma_f32_16x16x32_bf16(a1[mf], b1[nf], acc[mf][nf], 0, 0, 0);
    __builtin_amdgcn_s_setprio(0);
  }

  int rg = kq * 4;
#pragma unroll
  for (int mf = 0; mf < 4; mf++)
#pragma unroll
    for (int nf = 0; nf < 2; nf++) {
      size_t basei = (size_t)(m0 + wm + mf*16 + rg) * C_ + (size_t)(n0 + wn + nf*16 + r15);
#pragma unroll
      for (int r = 0; r < 4; r++)
        Co[basei + (size_t)r * C_] = acc[mf][nf][r];
    }
}

// ---------------- causal flash attention: R26 exact (best proven, ~40us) ----------------
__global__ __launch_bounds__(256, 2) void attn_kernel(const u16* __restrict__ qkv, u16* __restrict__ attnout) {
  __shared__ u16 Sm[4][4096];    // per wave: K tile [0..2047], V tile linear [2048..4095]
  int tid = threadIdx.x;
  int w = tid >> 6, lane = tid & 63;
  int q31 = lane & 31, hi = lane >> 5;
  int lid = blockIdx.x;
  int xcd = lid & 7, j = lid >> 3;
  int bh = xcd * 4 + (j & 3);
  int p = j >> 2;                // 0..31
  int b = bh >> 4, h = bh & 15;
  const u16* base = qkv + (size_t)b * T_ * N1_;

  u16* Ks = Sm[w];
  u16* Vl = Sm[w] + 2048;

  const u16* ksrc = base + C_ + h*HD_ + (size_t)(lane >> 3) * N1_
                    + (size_t)(((lane & 7) ^ ((lane >> 3) & 7)) * 8);
  const u16* vsrc = base + 2*C_ + h*HD_ + (size_t)(lane >> 3) * N1_
                    + (size_t)((lane & 7) * 8);
  const float QSC = 0.125f * 1.44269504088896f;

  int sA = 63 - p, sB = p;
  int qgA = sA * 32 + q31, qgB = sB * 32 + q31;
  int nktU = sA + 1;             // >= 33, all 4 waves active

  bf16x8 qfA[4], qfB[4];
  {
    const u16* qrowA = base + (size_t)qgA * N1_ + h * HD_;
    const u16* qrowB = base + (size_t)qgB * N1_ + h * HD_;
#pragma unroll
    for (int kk = 0; kk < 4; kk++) {
      bf16x8 ra = *reinterpret_cast<const bf16x8*>(qrowA + kk*16 + hi*8);
      bf16x8 rb = *reinterpret_cast<const bf16x8*>(qrowB + kk*16 + hi*8);
      const u16* pa = (const u16*)&ra;
      const u16* pb = (const u16*)&rb;
      u32x4 qa, qb;
#pragma unroll
      for (int jj = 0; jj < 4; jj++) {
        qa[jj] = cvtpk(bf2f(pa[2*jj]) * QSC, bf2f(pa[2*jj+1]) * QSC);
        qb[jj] = cvtpk(bf2f(pb[2*jj]) * QSC, bf2f(pb[2*jj+1]) * QSC);
      }
      qfA[kk] = __builtin_bit_cast(bf16x8, qa);
      qfB[kk] = __builtin_bit_cast(bf16x8, qb);
    }
  }

  f32x16 oaccA[2] = {}, oaccB[2] = {};
  float lA = 0.f, lB = 0.f;

  // ---- prologue: stage K(w) then V(w) via gload_lds (8 outstanding) ----
  {
    size_t off0 = (size_t)(w * 32) * N1_;
#pragma unroll
    for (int r = 0; r < 4; r++)
      gload_lds16(ksrc + off0 + (size_t)(8*r) * N1_, (char*)Ks + r*1024);
#pragma unroll
    for (int r = 0; r < 4; r++)
      gload_lds16(vsrc + off0 + (size_t)(8*r) * N1_, (char*)Vl + r*1024);
  }

  for (int kt = w; kt < nktU; kt += 4) {
    int kb = kt * 32;
    bool lastown = (kt + 4 >= nktU);
    bool actB = (kt <= sB);

    // ---- K(t) landed (V(t) + any K(t+4) remain countable) ----
    asm volatile("s_waitcnt vmcnt(4)" ::: "memory");

    // ---- QK^T (kf read once, both strips) ----
    f32x16 stA = {}, stB = {};
    if (actB) {
#pragma unroll
      for (int kk = 0; kk < 4; kk++) {
        bf16x8 kf = *reinterpret_cast<const bf16x8*>(
            &Ks[q31*64 + ((((kk<<1) | hi) ^ (q31 & 7)) << 3)]);
        stA = __builtin_amdgcn_mfma_f32_32x32x16_bf16(kf, qfA[kk], stA, 0, 0, 0);
        stB = __builtin_amdgcn_mfma_f32_32x32x16_bf16(kf, qfB[kk], stB, 0, 0, 0);
      }
    } else {
#pragma unroll
      for (int kk = 0; kk < 4; kk++) {
        bf16x8 kf = *reinterpret_cast<const bf16x8*>(
            &Ks[q31*64 + ((((kk<<1) | hi) ^ (q31 & 7)) << 3)]);
        stA = __builtin_amdgcn_mfma_f32_32x32x16_bf16(kf, qfA[kk], stA, 0, 0, 0);
      }
    }
    asm volatile("s_waitcnt lgkmcnt(0)" ::: "memory");   // Ks reads retired
    __builtin_amdgcn_sched_barrier(0);

    // ---- prefetch K(t+4) into Ks (safe: QK reads drained) ----
    if (!lastown) {
      size_t off = (size_t)(kb + 128) * N1_;
#pragma unroll
      for (int r = 0; r < 4; r++)
        gload_lds16(ksrc + off + (size_t)(8*r) * N1_, (char*)Ks + r*1024);
    }

    // ---- softmax + pack A ----
    if (kt == sA) {
#pragma unroll
      for (int r = 0; r < 16; r++) {
        int keyg = kb + (r&3) + 8*(r>>2) + 4*hi;
        if (keyg > qgA) stA[r] = -__builtin_inff();
      }
    }
    {
      float ts = 0.f;
#pragma unroll
      for (int r = 0; r < 16; r++) {
        float pp = exp2v(stA[r]);
        stA[r] = pp;
        ts += pp;
      }
      lA += ts;
    }
    bf16x8 pfA0, pfA1;
    {
      u32 pk[8];
#pragma unroll
      for (int m = 0; m < 8; m++) pk[m] = cvtpk(stA[2*m], stA[2*m+1]);
      asm volatile("v_permlane32_swap_b32 %0, %1" : "+v"(pk[0]), "+v"(pk[2]));
      asm volatile("v_permlane32_swap_b32 %0, %1" : "+v"(pk[1]), "+v"(pk[3]));
      asm volatile("v_permlane32_swap_b32 %0, %1" : "+v"(pk[4]), "+v"(pk[6]));
      asm volatile("v_permlane32_swap_b32 %0, %1" : "+v"(pk[5]), "+v"(pk[7]));
      u32x4 f0 = { pk[0], pk[1], pk[2], pk[3] };
      u32x4 f1 = { pk[4], pk[5], pk[6], pk[7] };
      pfA0 = __builtin_bit_cast(bf16x8, f0);
      pfA1 = __builtin_bit_cast(bf16x8, f1);
    }
    bf16x8 pfB0, pfB1;
    if (actB) {
      if (kt == sB) {
#pragma unroll
        for (int r = 0; r < 16; r++) {
          int keyg = kb + (r&3) + 8*(r>>2) + 4*hi;
          if (keyg > qgB) stB[r] = -__builtin_inff();
        }
      }
      {
        float ts = 0.f;
#pragma unroll
        for (int r = 0; r < 16; r++) {
          float pp = exp2v(stB[r]);
          stB[r] = pp;
          ts += pp;
        }
        lB += ts;
      }
      u32 pk[8];
#pragma unroll
      for (int m = 0; m < 8; m++) pk[m] = cvtpk(stB[2*m], stB[2*m+1]);
      asm volatile("v_permlane32_swap_b32 %0, %1" : "+v"(pk[0]), "+v"(pk[2]));
      asm volatile("v_permlane32_swap_b32 %0, %1" : "+v"(pk[1]), "+v"(pk[3]));
      asm volatile("v_permlane32_swap_b32 %0, %1" : "+v"(pk[4]), "+v"(pk[6]));
      asm volatile("v_permlane32_swap_b32 %0, %1" : "+v"(pk[5]), "+v"(pk[7]));
      u32x4 f0 = { pk[0], pk[1], pk[2], pk[3] };
      u32x4 f1 = { pk[4], pk[5], pk[6], pk[7] };
      pfB0 = __builtin_bit_cast(bf16x8, f0);
      pfB1 = __builtin_bit_cast(bf16x8, f1);
    }

    // ---- V(t) landed in LDS (K(t+4) may remain in flight) ----
    if (!lastown) asm volatile("s_waitcnt vmcnt(4)" ::: "memory");
    else          asm volatile("s_waitcnt vmcnt(0)" ::: "memory");

    // ---- PV: O^T += V^T * P^T; vf = 8x ds_read_u16 from linear V ----
    if (actB) {
#pragma unroll
      for (int dt = 0; dt < 2; dt++)
#pragma unroll
        for (int ks = 0; ks < 2; ks++) {
          u16 tv[8];
#pragma unroll
          for (int jj = 0; jj < 8; jj++)
            tv[jj] = Vl[(16*ks + 8*hi + jj)*64 + 32*dt + q31];
          bf16x8 vf = *reinterpret_cast<const bf16x8*>(tv);
          oaccA[dt] = __builtin_amdgcn_mfma_f32_32x32x16_bf16(vf, ks ? pfA1 : pfA0, oaccA[dt], 0, 0, 0);
          oaccB[dt] = __builtin_amdgcn_mfma_f32_32x32x16_bf16(vf, ks ? pfB1 : pfB0, oaccB[dt], 0, 0, 0);
        }
    } else {
#pragma unroll
      for (int dt = 0; dt < 2; dt++)
#pragma unroll
        for (int ks = 0; ks < 2; ks++) {
          u16 tv[8];
#pragma unroll
          for (int jj = 0; jj < 8; jj++)
            tv[jj] = Vl[(16*ks + 8*hi + jj)*64 + 32*dt + q31];
          bf16x8 vf = *reinterpret_cast<const bf16x8*>(tv);
          oaccA[dt] = __builtin_amdgcn_mfma_f32_32x32x16_bf16(vf, ks ? pfA1 : pfA0, oaccA[dt], 0, 0, 0);
        }
    }
    LGKM0();                      // Vl reads retired before V(t+4) prefetch

    // ---- prefetch V(t+4) into Vl ----
    if (!lastown) {
      size_t off = (size_t)(kb + 128) * N1_;
#pragma unroll
      for (int r = 0; r < 4; r++)
        gload_lds16(vsrc + off + (size_t)(8*r) * N1_, (char*)Vl + r*1024);
    }
  }
  lA += __shfl_xor(lA, 32);
  lB += __shfl_xor(lB, 32);

  // ---- merge strip A (4-way) ----
  __syncthreads();
  if (w) {
    float* park = (float*)Sm[w];
#pragma unroll
    for (int dt = 0; dt < 2; dt++)
#pragma unroll
      for (int r = 0; r < 16; r++) park[(dt*16 + r)*64 + lane] = oaccA[dt][r];
    float* ml = (float*)Sm[0];
    ml[(w-1)*64 + lane] = lA;
  }
  __syncthreads();
  if (w == 0) {
    const float* ml = (const float*)Sm[0];
    float linv = 1.f / (lA + ml[lane] + ml[64 + lane] + ml[128 + lane]);
    const float* p1 = (const float*)Sm[1];
    const float* p2 = (const float*)Sm[2];
    const float* p3 = (const float*)Sm[3];
    u16* orow = attnout + (size_t)(b*T_ + qgA) * C_ + h*HD_;
#pragma unroll
    for (int dt = 0; dt < 2; dt++)
#pragma unroll
      for (int m = 0; m < 8; m++) {
        int e0 = (dt*16 + 2*m)*64 + lane, e1 = e0 + 64;
        float v0 = (oaccA[dt][2*m]   + p1[e0] + p2[e0] + p3[e0]) * linv;
        float v1 = (oaccA[dt][2*m+1] + p1[e1] + p2[e1] + p3[e1]) * linv;
        int d = 32*dt + 2*(m&1) + 8*(m>>1) + 4*hi;
        *reinterpret_cast<u32*>(orow + d) = cvtpk(v0, v1);
      }
  }
  __syncthreads();
  // ---- merge strip B (4-way) ----
  if (w) {
    float* park = (float*)Sm[w];
#pragma unroll
    for (int dt = 0; dt < 2; dt++)
#pragma unroll
      for (int r = 0; r < 16; r++) park[(dt*16 + r)*64 + lane] = oaccB[dt][r];
    float* ml = (float*)Sm[0];
    ml[(w-1)*64 + lane] = lB;
  }
  __syncthreads();
  if (w == 0) {
    const float* ml = (const float*)Sm[0];
    float linv = 1.f / (lB + ml[lane] + ml[64 + lane] + ml[128 + lane]);
    const float* p1 = (const float*)Sm[1];
    const float* p2 = (const float*)Sm[2];
    const float* p3 = (const float*)Sm[3];
    u16* orow = attnout + (size_t)(b*T_ + qgB) * C_ + h*HD_;
#pragma unroll
    for (int dt = 0; dt < 2; dt++)
#pragma unroll
      for (int m = 0; m < 8; m++) {
        int e0 = (dt*16 + 2*m)*64 + lane, e1 = e0 + 64;
        float v0 = (oaccB[dt][2*m]   + p1[e0] + p2[e0] + p3[e0]) * linv;
        float v1 = (oaccB[dt][2*m+1] + p1[e1] + p2[e1] + p3[e1]) * linv;
        int d = 32*dt + 2*(m&1) + 8*(m>>1) + 4*hi;
        *reinterpret_cast<u32*>(orow + d) = cvtpk(v0, v1);
      }
  }
}

extern "C" void kernel_launch(void* const* d_in, const int* in_sizes, int n_in,
                              void* d_out, int out_size, void* d_ws, size_t ws_size,
                              hipStream_t stream) {
  const float* x     = (const float*)d_in[0];
  const float* w_qkv = (const float*)d_in[1];
  const float* w_out = (const float*)d_in[2];
  float* out = (float*)d_out;
  char* ws = (char*)d_ws;
  u16* xb    = (u16*)(ws);                         // 8 MB  : x bf16 (4096 x 1024)
  u16* wqkvT = (u16*)(ws + ((size_t)8  << 20));    // 6 MB  : w_qkv^T bf16 (3072 x 1024)
  u16* woutT = (u16*)(ws + ((size_t)14 << 20));    // 2 MB  : w_out^T bf16 (1024 x 1024)
  u16* qkvb  = (u16*)(ws + ((size_t)16 << 20));    // 24 MB : qkv bf16 (4096 x 3072)
  u16* attnb = (u16*)(ws + ((size_t)40 << 20));    // 8 MB  : attn out bf16 (4096 x 1024)

  prep_k<<<8192, 256, 0, stream>>>(x, w_qkv, w_out, xb, wqkvT, woutT);
  gemm256<<<dim3(16, 16), 512, 0, stream>>>(xb, wqkvT, qkvb);
  attn_kernel<<<1024, 256, 0, stream>>>(qkvb, attnb);
  gemm128<<<dim3(8, 32), 512, 0, stream>>>(attnb, woutT, out);
}